// Round 1
// baseline (353.763 us; speedup 1.0000x reference)
//
#include <hip/hip_runtime.h>
#include <hip/hip_bf16.h>

#define M_DIM 4096
#define N_DIM 4096
#define K_DIM 4096

typedef __attribute__((ext_vector_type(8))) short bf16x8;
typedef __attribute__((ext_vector_type(4))) float f32x4;

typedef __attribute__((address_space(1))) const void GV;
typedef __attribute__((address_space(3))) void LV;

static __device__ __forceinline__ unsigned short f2bf(float f) {
  // RNE fp32 -> bf16
  unsigned int u = __float_as_uint(f);
  unsigned int r = (u + 0x7fffu + ((u >> 16) & 1u)) >> 16;
  return (unsigned short)r;
}

// ---------------------------------------------------------------------------
// Kernel 1: partial Hadamard (G=64 groups of had_dim=64) + per-token absmax
// quantize-dequantize, output bf16. One wave per token; lane = position-in-
// group (d), registers hold the 64-element group column -> in-register FWHT.
// ---------------------------------------------------------------------------
__global__ __launch_bounds__(64) void hadquant_kernel(const float* __restrict__ x,
                                                      unsigned short* __restrict__ xq) {
  const int tok = blockIdx.x;
  const int lane = threadIdx.x;  // 0..63 = d within group
  const float* xp = x + (size_t)tok * 4096;

  float v[64];
#pragma unroll
  for (int g = 0; g < 64; ++g) v[g] = xp[g * 64 + lane];

  // FWHT across the 64 groups == Sylvester Hadamard  (y = H x)
#pragma unroll
  for (int s = 1; s < 64; s <<= 1) {
#pragma unroll
    for (int i = 0; i < 64; ++i) {
      if ((i & s) == 0) {
        float a = v[i], b = v[i | s];
        v[i] = a + b;
        v[i | s] = a - b;
      }
    }
  }

  float amax = 0.f;
#pragma unroll
  for (int i = 0; i < 64; ++i) {
    v[i] *= 0.125f;  // 1/sqrt(64)
    amax = fmaxf(amax, fabsf(v[i]));
  }
  // wave-wide (per-token) max
#pragma unroll
  for (int off = 32; off >= 1; off >>= 1) amax = fmaxf(amax, __shfl_xor(amax, off, 64));

  const float s = fmaxf(amax * (1.0f / 127.0f), 1e-5f);

  unsigned short* op = xq + (size_t)tok * 4096;
#pragma unroll
  for (int g = 0; g < 64; ++g) {
    float d = rintf(v[g] / s) * s;  // rintf = round-half-even, matches jnp.round
    op[g * 64 + lane] = f2bf(d);
  }
}

// ---------------------------------------------------------------------------
// Kernel 2: weight fp32 -> bf16 (weight already QDQ'd at setup time)
// ---------------------------------------------------------------------------
__global__ __launch_bounds__(256) void wconv_kernel(const float4* __restrict__ w,
                                                    ushort4* __restrict__ wq, int n4) {
  int i = blockIdx.x * blockDim.x + threadIdx.x;
  if (i < n4) {
    float4 a = w[i];
    ushort4 o;
    o.x = f2bf(a.x);
    o.y = f2bf(a.y);
    o.z = f2bf(a.z);
    o.w = f2bf(a.w);
    wq[i] = o;
  }
}

// ---------------------------------------------------------------------------
// Kernel 3: C[m][n] = sum_k A[m][k] * B[n][k] + bias[n]   (both row-major, bf16)
// 128x128 block tile, BK=32, 4 waves in 2x2, each wave 4x4 of 16x16x32 MFMA.
// Staging via global_load_lds width=16 (lane-order contiguous LDS, no pad).
// ---------------------------------------------------------------------------
__global__ __launch_bounds__(256) void gemm_bt_bias(const unsigned short* __restrict__ A,
                                                    const unsigned short* __restrict__ B,
                                                    const float* __restrict__ bias,
                                                    float* __restrict__ C) {
  __shared__ unsigned short As[128 * 32];
  __shared__ unsigned short Bs[128 * 32];

  const int tid = threadIdx.x;
  const int lane = tid & 63;
  const int wave = tid >> 6;
  const int bm = blockIdx.y, bn = blockIdx.x;
  const int wm = wave >> 1, wn = wave & 1;

  // ---- staging addresses: segment = 16B = 8 bf16; row = 32 elems = 4 segs
  const int rowA = tid >> 2;          // 0..63
  const int off8 = (tid & 3) * 8;     // 0,8,16,24 elements within row
  const unsigned short* gA0 = A + (size_t)(bm * 128 + rowA) * K_DIM + off8;
  const unsigned short* gA1 = gA0 + (size_t)64 * K_DIM;
  const unsigned short* gB0 = B + (size_t)(bn * 128 + rowA) * K_DIM + off8;
  const unsigned short* gB1 = gB0 + (size_t)64 * K_DIM;
  unsigned short* lA0 = &As[tid * 8];
  unsigned short* lA1 = &As[(tid + 256) * 8];
  unsigned short* lB0 = &Bs[tid * 8];
  unsigned short* lB1 = &Bs[(tid + 256) * 8];

  // ---- fragment LDS offsets
  const int quad = lane >> 4;   // 0..3
  const int r16 = lane & 15;    // 0..15
  int aoff[4], boff[4];
#pragma unroll
  for (int i = 0; i < 4; ++i) aoff[i] = (wm * 64 + i * 16 + r16) * 32 + quad * 8;
#pragma unroll
  for (int j = 0; j < 4; ++j) boff[j] = (wn * 64 + j * 16 + r16) * 32 + quad * 8;

  f32x4 acc[4][4];
#pragma unroll
  for (int i = 0; i < 4; ++i)
#pragma unroll
    for (int j = 0; j < 4; ++j) acc[i][j] = {0.f, 0.f, 0.f, 0.f};

  for (int kt = 0; kt < K_DIM / 32; ++kt) {
    __syncthreads();  // previous tile fully consumed before overwrite
    const int ke = kt * 32;
    __builtin_amdgcn_global_load_lds((GV*)(gA0 + ke), (LV*)lA0, 16, 0, 0);
    __builtin_amdgcn_global_load_lds((GV*)(gA1 + ke), (LV*)lA1, 16, 0, 0);
    __builtin_amdgcn_global_load_lds((GV*)(gB0 + ke), (LV*)lB0, 16, 0, 0);
    __builtin_amdgcn_global_load_lds((GV*)(gB1 + ke), (LV*)lB1, 16, 0, 0);
    __syncthreads();  // drains vmcnt (compiler emits waitcnt before s_barrier)

    bf16x8 af[4], bfr[4];
#pragma unroll
    for (int i = 0; i < 4; ++i) af[i] = *(const bf16x8*)&As[aoff[i]];
#pragma unroll
    for (int j = 0; j < 4; ++j) bfr[j] = *(const bf16x8*)&Bs[boff[j]];

#pragma unroll
    for (int i = 0; i < 4; ++i)
#pragma unroll
      for (int j = 0; j < 4; ++j)
        acc[i][j] = __builtin_amdgcn_mfma_f32_16x16x32_bf16(af[i], bfr[j], acc[i][j], 0, 0, 0);
  }

  // ---- epilogue: C/D layout col=lane&15, row=quad*4+reg  (verified m89/m91)
  float bv[4];
#pragma unroll
  for (int j = 0; j < 4; ++j) bv[j] = bias[bn * 128 + wn * 64 + j * 16 + r16];

#pragma unroll
  for (int i = 0; i < 4; ++i) {
    const int rowg = bm * 128 + wm * 64 + i * 16 + quad * 4;
#pragma unroll
    for (int j = 0; j < 4; ++j) {
      const int colg = bn * 128 + wn * 64 + j * 16 + r16;
#pragma unroll
      for (int r = 0; r < 4; ++r) {
        C[(size_t)(rowg + r) * N_DIM + colg] = acc[i][j][r] + bv[j];
      }
    }
  }
}

// ---------------------------------------------------------------------------
extern "C" void kernel_launch(void* const* d_in, const int* in_sizes, int n_in,
                              void* d_out, int out_size, void* d_ws, size_t ws_size,
                              hipStream_t stream) {
  const float* x = (const float*)d_in[0];     // (2,2048,4096) fp32
  const float* w = (const float*)d_in[1];     // (4096,4096) fp32 (pre-quantized)
  const float* bias = (const float*)d_in[2];  // (4096,) fp32
  // d_in[3] = had_dim (64), hard-coded in the kernels

  unsigned short* xq = (unsigned short*)d_ws;                  // 32 MB bf16
  unsigned short* wq = xq + (size_t)M_DIM * K_DIM;             // 32 MB bf16
  float* out = (float*)d_out;

  hadquant_kernel<<<M_DIM, 64, 0, stream>>>(x, xq);
  wconv_kernel<<<(N_DIM * K_DIM / 4 + 255) / 256, 256, 0, stream>>>(
      (const float4*)w, (ushort4*)wq, N_DIM * K_DIM / 4);

  dim3 grid(N_DIM / 128, M_DIM / 128);
  gemm_bt_bias<<<grid, 256, 0, stream>>>(xq, wq, bias, out);
}

// Round 2
// 345.684 us; speedup vs baseline: 1.0234x; 1.0234x over previous
//
#include <hip/hip_runtime.h>
#include <hip/hip_bf16.h>

#define M_DIM 4096
#define N_DIM 4096
#define K_DIM 4096

typedef __attribute__((ext_vector_type(8))) short bf16x8;
typedef __attribute__((ext_vector_type(4))) float f32x4;
typedef __attribute__((ext_vector_type(16))) float f32x16;

typedef __attribute__((address_space(1))) const void GV;
typedef __attribute__((address_space(3))) void LV;

static __device__ __forceinline__ unsigned short f2bf(float f) {
  // RNE fp32 -> bf16
  unsigned int u = __float_as_uint(f);
  unsigned int r = (u + 0x7fffu + ((u >> 16) & 1u)) >> 16;
  return (unsigned short)r;
}

// ---------------------------------------------------------------------------
// Fused pre-kernel. Blocks [0, HAD_BLOCKS): hadamard+quant (wave per token).
// Blocks [HAD_BLOCKS, HAD_BLOCKS+WCONV_BLOCKS): weight fp32->bf16 cast.
// ---------------------------------------------------------------------------
#define HAD_BLOCKS 1024          // 4 waves/block, 1 token/wave -> 4096 tokens
#define WCONV_BLOCKS 8192        // 256 thr * 8 elems = 2048 elems/block

__global__ __launch_bounds__(256) void hadwconv_kernel(const float* __restrict__ x,
                                                       const float* __restrict__ w,
                                                       unsigned short* __restrict__ xq,
                                                       unsigned short* __restrict__ wq) {
  if (blockIdx.x >= HAD_BLOCKS) {
    // ---- weight cast: 8 floats / thread, 16B in x2 / 16B out
    const size_t base = ((size_t)(blockIdx.x - HAD_BLOCKS) * 256 + threadIdx.x) * 8;
    float4 a = *(const float4*)(w + base);
    float4 b = *(const float4*)(w + base + 4);
    ushort4 lo, hi;
    lo.x = f2bf(a.x); lo.y = f2bf(a.y); lo.z = f2bf(a.z); lo.w = f2bf(a.w);
    hi.x = f2bf(b.x); hi.y = f2bf(b.y); hi.z = f2bf(b.z); hi.w = f2bf(b.w);
    uint4 o;
    o.x = (unsigned)lo.x | ((unsigned)lo.y << 16);
    o.y = (unsigned)lo.z | ((unsigned)lo.w << 16);
    o.z = (unsigned)hi.x | ((unsigned)hi.y << 16);
    o.w = (unsigned)hi.z | ((unsigned)hi.w << 16);
    *(uint4*)(wq + base) = o;
    return;
  }

  // ---- hadamard (G=64 FWHT over groups) + per-token absmax QDQ -> bf16
  const int wave = threadIdx.x >> 6;
  const int lane = threadIdx.x & 63;
  const int tok = blockIdx.x * 4 + wave;
  const int gs = lane >> 4;   // which quarter of g-space this lane's chunks sit in
  const int q = lane & 15;    // d-quad: d = q*4 .. q*4+3
  const float* xp = x + (size_t)tok * 4096;

  // lane holds g = gl*4 + gs for gl = 0..15, each as a float4 over d
  float4 v[16];
#pragma unroll
  for (int gl = 0; gl < 16; ++gl)
    v[gl] = *(const float4*)(xp + (gl * 4 + gs) * 64 + q * 4);

  // in-lane FWHT stages: g-bit differences 4,8,16,32 <=> gl-bit 1,2,4,8
#pragma unroll
  for (int s = 1; s < 16; s <<= 1) {
#pragma unroll
    for (int i = 0; i < 16; ++i) {
      if ((i & s) == 0) {
        float4 a = v[i], b = v[i | s];
        v[i].x = a.x + b.x; v[i].y = a.y + b.y; v[i].z = a.z + b.z; v[i].w = a.w + b.w;
        v[i | s].x = a.x - b.x; v[i | s].y = a.y - b.y;
        v[i | s].z = a.z - b.z; v[i | s].w = a.w - b.w;
      }
    }
  }
  // cross-lane stages: g-bit 1 <=> lane^16 (gs bit 0), g-bit 2 <=> lane^32
#pragma unroll
  for (int st = 0; st < 2; ++st) {
    const int L = 16 << st;
    const bool hi_half = (lane & L) != 0;
#pragma unroll
    for (int i = 0; i < 16; ++i) {
      float4 t;
      t.x = __shfl_xor(v[i].x, L, 64);
      t.y = __shfl_xor(v[i].y, L, 64);
      t.z = __shfl_xor(v[i].z, L, 64);
      t.w = __shfl_xor(v[i].w, L, 64);
      if (hi_half) {
        v[i].x = t.x - v[i].x; v[i].y = t.y - v[i].y;
        v[i].z = t.z - v[i].z; v[i].w = t.w - v[i].w;
      } else {
        v[i].x = v[i].x + t.x; v[i].y = v[i].y + t.y;
        v[i].z = v[i].z + t.z; v[i].w = v[i].w + t.w;
      }
    }
  }

  float amax = 0.f;
#pragma unroll
  for (int i = 0; i < 16; ++i) {
    v[i].x *= 0.125f; v[i].y *= 0.125f; v[i].z *= 0.125f; v[i].w *= 0.125f;
    amax = fmaxf(amax, fmaxf(fmaxf(fabsf(v[i].x), fabsf(v[i].y)),
                             fmaxf(fabsf(v[i].z), fabsf(v[i].w))));
  }
#pragma unroll
  for (int off = 32; off >= 1; off >>= 1) amax = fmaxf(amax, __shfl_xor(amax, off, 64));

  const float s = fmaxf(amax * (1.0f / 127.0f), 1e-5f);
  const float sinv = 1.0f / s;

  unsigned short* op = xq + (size_t)tok * 4096;
#pragma unroll
  for (int gl = 0; gl < 16; ++gl) {
    ushort4 o;
    o.x = f2bf(rintf(v[gl].x * sinv) * s);
    o.y = f2bf(rintf(v[gl].y * sinv) * s);
    o.z = f2bf(rintf(v[gl].z * sinv) * s);
    o.w = f2bf(rintf(v[gl].w * sinv) * s);
    *(ushort4*)(op + (gl * 4 + gs) * 64 + q * 4) = o;
  }
}

// ---------------------------------------------------------------------------
// GEMM: C[m][n] = sum_k A[m][k]*B[n][k] + bias[n], A/B bf16 row-major, C fp32.
// 128x128 tile, BK=32, 4 waves 2x2, each wave 2x2 of 32x32x16 MFMA.
// LDS rotate-swizzle: row r's 16B segment `gseg` lives in slot (gseg+(r>>1))&3
// -> ds_read_b128 hits all 32 banks over every 8 rows (min 8-cyc service).
// Staging keeps LDS dest = uniform base + lane*16 (global_load_lds constraint)
// by permuting which GLOBAL segment each thread fetches instead.
// ---------------------------------------------------------------------------
__global__ __launch_bounds__(256) void gemm_bt_bias(const unsigned short* __restrict__ A,
                                                    const unsigned short* __restrict__ B,
                                                    const float* __restrict__ bias,
                                                    float* __restrict__ C) {
  __shared__ unsigned short As[128 * 32];
  __shared__ unsigned short Bs[128 * 32];

  const int tid = threadIdx.x;
  const int lane = tid & 63;
  const int wave = tid >> 6;
  const int bm = blockIdx.y, bn = blockIdx.x;
  const int wm = wave >> 1, wn = wave & 1;

  // ---- staging: thread tid owns LDS row tid>>2, slot tid&3 (dest = tid*16B).
  //      It must fetch global segment gseg s.t. (gseg + (row>>1))&3 == slot.
  const int srow = tid >> 2;
  const int sslot = tid & 3;
  const int sgseg = (sslot - (srow >> 1)) & 3;
  const unsigned short* gA0 = A + (size_t)(bm * 128 + srow) * K_DIM + sgseg * 8;
  const unsigned short* gA1 = gA0 + (size_t)64 * K_DIM;
  const unsigned short* gB0 = B + (size_t)(bn * 128 + srow) * K_DIM + sgseg * 8;
  const unsigned short* gB1 = gB0 + (size_t)64 * K_DIM;
  unsigned short* lA0 = &As[tid * 8];
  unsigned short* lA1 = &As[(tid + 256) * 8];
  unsigned short* lB0 = &Bs[tid * 8];
  unsigned short* lB1 = &Bs[(tid + 256) * 8];

  // ---- fragment LDS byte offsets (element offsets here, shorts)
  //      A-frag (i, ks): row = wm*64+i*32+(lane&31), gseg = ks*2+(lane>>5)
  const int m32 = lane & 31;
  const int half = lane >> 5;
  int aoff[2][2], boff[2][2];
#pragma unroll
  for (int i = 0; i < 2; ++i)
#pragma unroll
    for (int ks = 0; ks < 2; ++ks) {
      {
        int row = wm * 64 + i * 32 + m32;
        int gseg = ks * 2 + half;
        int slot = (gseg + (row >> 1)) & 3;
        aoff[i][ks] = row * 32 + slot * 8;
      }
      {
        int row = wn * 64 + i * 32 + m32;
        int gseg = ks * 2 + half;
        int slot = (gseg + (row >> 1)) & 3;
        boff[i][ks] = row * 32 + slot * 8;
      }
    }

  f32x16 acc[2][2];
#pragma unroll
  for (int i = 0; i < 2; ++i)
#pragma unroll
    for (int j = 0; j < 2; ++j)
#pragma unroll
      for (int r = 0; r < 16; ++r) acc[i][j][r] = 0.f;

  for (int kt = 0; kt < K_DIM / 32; ++kt) {
    __syncthreads();
    const int ke = kt * 32;
    __builtin_amdgcn_global_load_lds((GV*)(gA0 + ke), (LV*)lA0, 16, 0, 0);
    __builtin_amdgcn_global_load_lds((GV*)(gA1 + ke), (LV*)lA1, 16, 0, 0);
    __builtin_amdgcn_global_load_lds((GV*)(gB0 + ke), (LV*)lB0, 16, 0, 0);
    __builtin_amdgcn_global_load_lds((GV*)(gB1 + ke), (LV*)lB1, 16, 0, 0);
    __syncthreads();

    bf16x8 af[2][2], bfr[2][2];
#pragma unroll
    for (int i = 0; i < 2; ++i)
#pragma unroll
      for (int ks = 0; ks < 2; ++ks) {
        af[i][ks] = *(const bf16x8*)&As[aoff[i][ks]];
        bfr[i][ks] = *(const bf16x8*)&Bs[boff[i][ks]];
      }

#pragma unroll
    for (int ks = 0; ks < 2; ++ks)
#pragma unroll
      for (int i = 0; i < 2; ++i)
#pragma unroll
        for (int j = 0; j < 2; ++j)
          acc[i][j] = __builtin_amdgcn_mfma_f32_32x32x16_bf16(af[i][ks], bfr[j][ks],
                                                              acc[i][j], 0, 0, 0);
  }

  // ---- epilogue: C/D layout col=lane&31, row=(r&3)+8*(r>>2)+4*(lane>>5)
  float bv[2];
#pragma unroll
  for (int j = 0; j < 2; ++j) bv[j] = bias[bn * 128 + wn * 64 + j * 32 + m32];

#pragma unroll
  for (int i = 0; i < 2; ++i) {
#pragma unroll
    for (int j = 0; j < 2; ++j) {
      const int colg = bn * 128 + wn * 64 + j * 32 + m32;
#pragma unroll
      for (int r = 0; r < 16; ++r) {
        const int rowg = bm * 128 + wm * 64 + i * 32 + (r & 3) + 8 * (r >> 2) + 4 * half;
        C[(size_t)rowg * N_DIM + colg] = acc[i][j][r] + bv[j];
      }
    }
  }
}

// ---------------------------------------------------------------------------
extern "C" void kernel_launch(void* const* d_in, const int* in_sizes, int n_in,
                              void* d_out, int out_size, void* d_ws, size_t ws_size,
                              hipStream_t stream) {
  const float* x = (const float*)d_in[0];     // (2,2048,4096) fp32
  const float* w = (const float*)d_in[1];     // (4096,4096) fp32 (pre-quantized)
  const float* bias = (const float*)d_in[2];  // (4096,) fp32

  unsigned short* xq = (unsigned short*)d_ws;             // 32 MB bf16
  unsigned short* wq = xq + (size_t)M_DIM * K_DIM;        // 32 MB bf16
  float* out = (float*)d_out;

  hadwconv_kernel<<<HAD_BLOCKS + WCONV_BLOCKS, 256, 0, stream>>>(x, w, xq, wq);

  dim3 grid(N_DIM / 128, M_DIM / 128);
  gemm_bt_bias<<<grid, 256, 0, stream>>>(xq, wq, bias, out);
}

// Round 3
// 271.450 us; speedup vs baseline: 1.3032x; 1.2735x over previous
//
#include <hip/hip_runtime.h>
#include <hip/hip_bf16.h>

#define M_DIM 4096
#define N_DIM 4096
#define K_DIM 4096

typedef __attribute__((ext_vector_type(4))) int i32x4;
typedef __attribute__((ext_vector_type(16))) int i32x16;

typedef __attribute__((address_space(1))) const void GV;
typedef __attribute__((address_space(3))) void LV;

// ---------------------------------------------------------------------------
// Fused pre-kernel.
//  blocks [0,1024):    hadamard (FWHT over 64 groups) + per-token absmax
//                      int8 quant; writes xq (i8) + sx (f32/token).
//  blocks [1024,2048): weight int8 recovery: per-row scale = absmax/127
//                      (exact inverse of setup-time per-channel QDQ);
//                      writes wq (i8) + sw (f32/row).
// ---------------------------------------------------------------------------
__global__ __launch_bounds__(256) void prequant_kernel(const float* __restrict__ x,
                                                       const float* __restrict__ w,
                                                       char* __restrict__ xq,
                                                       char* __restrict__ wq,
                                                       float* __restrict__ sx,
                                                       float* __restrict__ sw) {
  const int wave = threadIdx.x >> 6;
  const int lane = threadIdx.x & 63;

  if (blockIdx.x >= 1024) {
    // ---- weight row: recover integer codes exactly
    const int row = (blockIdx.x - 1024) * 4 + wave;
    const float* wp = w + (size_t)row * 4096;
    float4 v[16];
#pragma unroll
    for (int c = 0; c < 16; ++c) v[c] = *(const float4*)(wp + c * 256 + lane * 4);
    float amax = 0.f;
#pragma unroll
    for (int c = 0; c < 16; ++c)
      amax = fmaxf(amax, fmaxf(fmaxf(fabsf(v[c].x), fabsf(v[c].y)),
                               fmaxf(fabsf(v[c].z), fabsf(v[c].w))));
#pragma unroll
    for (int off = 32; off >= 1; off >>= 1) amax = fmaxf(amax, __shfl_xor(amax, off, 64));
    amax = fmaxf(amax, 1e-30f);
    const float inv = 127.0f / amax;  // w = iw*s with amax = 127*s  ->  w*inv = iw
    char* op = wq + (size_t)row * 4096;
#pragma unroll
    for (int c = 0; c < 16; ++c) {
      char4 o;
      o.x = (char)rintf(v[c].x * inv);
      o.y = (char)rintf(v[c].y * inv);
      o.z = (char)rintf(v[c].z * inv);
      o.w = (char)rintf(v[c].w * inv);
      *(char4*)(op + c * 256 + lane * 4) = o;
    }
    if (lane == 0) sw[row] = amax * (1.0f / 127.0f);
    return;
  }

  // ---- hadamard + per-token int8 quant
  const int tok = blockIdx.x * 4 + wave;
  const int gs = lane >> 4;  // quarter of g-space
  const int q = lane & 15;   // d-quad: d = q*4..q*4+3
  const float* xp = x + (size_t)tok * 4096;

  float4 v[16];  // lane holds g = gl*4+gs, gl=0..15, float4 over d
#pragma unroll
  for (int gl = 0; gl < 16; ++gl)
    v[gl] = *(const float4*)(xp + (gl * 4 + gs) * 64 + q * 4);

  // in-lane FWHT stages (g-bits 4,8,16,32 <=> gl-bits 1,2,4,8)
#pragma unroll
  for (int s = 1; s < 16; s <<= 1) {
#pragma unroll
    for (int i = 0; i < 16; ++i) {
      if ((i & s) == 0) {
        float4 a = v[i], b = v[i | s];
        v[i].x = a.x + b.x; v[i].y = a.y + b.y; v[i].z = a.z + b.z; v[i].w = a.w + b.w;
        v[i | s].x = a.x - b.x; v[i | s].y = a.y - b.y;
        v[i | s].z = a.z - b.z; v[i | s].w = a.w - b.w;
      }
    }
  }
  // cross-lane stages: g-bit 1 <=> lane^16, g-bit 2 <=> lane^32
#pragma unroll
  for (int st = 0; st < 2; ++st) {
    const int L = 16 << st;
    const bool hi = (lane & L) != 0;
#pragma unroll
    for (int i = 0; i < 16; ++i) {
      float4 t;
      t.x = __shfl_xor(v[i].x, L, 64);
      t.y = __shfl_xor(v[i].y, L, 64);
      t.z = __shfl_xor(v[i].z, L, 64);
      t.w = __shfl_xor(v[i].w, L, 64);
      if (hi) {
        v[i].x = t.x - v[i].x; v[i].y = t.y - v[i].y;
        v[i].z = t.z - v[i].z; v[i].w = t.w - v[i].w;
      } else {
        v[i].x += t.x; v[i].y += t.y; v[i].z += t.z; v[i].w += t.w;
      }
    }
  }

  float amax = 0.f;
#pragma unroll
  for (int i = 0; i < 16; ++i) {
    v[i].x *= 0.125f; v[i].y *= 0.125f; v[i].z *= 0.125f; v[i].w *= 0.125f;  // 1/sqrt(64)
    amax = fmaxf(amax, fmaxf(fmaxf(fabsf(v[i].x), fabsf(v[i].y)),
                             fmaxf(fabsf(v[i].z), fabsf(v[i].w))));
  }
#pragma unroll
  for (int off = 32; off >= 1; off >>= 1) amax = fmaxf(amax, __shfl_xor(amax, off, 64));

  const float s = fmaxf(amax * (1.0f / 127.0f), 1e-5f);  // reference clip
  const float inv = 1.0f / s;

  char* op = xq + (size_t)tok * 4096;
#pragma unroll
  for (int gl = 0; gl < 16; ++gl) {
    char4 o;
    o.x = (char)rintf(v[gl].x * inv);
    o.y = (char)rintf(v[gl].y * inv);
    o.z = (char)rintf(v[gl].z * inv);
    o.w = (char)rintf(v[gl].w * inv);
    *(char4*)(op + (gl * 4 + gs) * 64 + q * 4) = o;
  }
  if (lane == 0) sx[tok] = s;
}

// ---------------------------------------------------------------------------
// Exact int8 GEMM: C[m][n] = sx[m]*sw[n] * (sum_k ix[m][k]*iw[n][k]) + bias[n]
// 128x128 tile, BK=64 (i8), 4 waves 2x2, each wave 2x2 of mfma_i32_32x32x32_i8.
// LDS row = 64 B; slot-XOR swizzle (slot = seg ^ (row&3)) keeps staging
// contiguous per global_load_lds while frag ds_read_b128 hits all 32 banks.
// A-operand layout assumed contiguous-per-lane: k = (lane>>5)*16 + j
// (gfx950 2xK convention, verified for f16 16x16x32 / f8f6f4).
// ---------------------------------------------------------------------------
__global__ __launch_bounds__(256) void gemm_i8(const char* __restrict__ A,
                                               const char* __restrict__ B,
                                               const float* __restrict__ sx,
                                               const float* __restrict__ sw,
                                               const float* __restrict__ bias,
                                               float* __restrict__ C) {
  __shared__ char As[128 * 64];
  __shared__ char Bs[128 * 64];

  const int tid = threadIdx.x;
  const int lane = tid & 63;
  const int wave = tid >> 6;
  const int bm = blockIdx.y, bn = blockIdx.x;
  const int wm = wave >> 1, wn = wave & 1;

  // ---- staging: thread tid -> LDS row tid>>2, slot tid&3, dest = tid*16B.
  //      fetch global 16B-segment seg = slot ^ (row&3).
  const int srow = tid >> 2;
  const int sseg = (tid & 3) ^ (srow & 3);
  const char* gA0 = A + (size_t)(bm * 128 + srow) * K_DIM + sseg * 16;
  const char* gA1 = gA0 + (size_t)64 * K_DIM;
  const char* gB0 = B + (size_t)(bn * 128 + srow) * K_DIM + sseg * 16;
  const char* gB1 = gB0 + (size_t)64 * K_DIM;
  char* lA0 = &As[tid * 16];
  char* lA1 = &As[(tid + 256) * 16];
  char* lB0 = &Bs[tid * 16];
  char* lB1 = &Bs[(tid + 256) * 16];

  // ---- fragment offsets: row r, logical seg = ks*2 + (lane>>5), slot = seg^(r&3)
  const int m32 = lane & 31;
  const int half = lane >> 5;
  int aoff[2][2], boff[2][2];
#pragma unroll
  for (int i = 0; i < 2; ++i)
#pragma unroll
    for (int ks = 0; ks < 2; ++ks) {
      const int slot = ((ks * 2 + half) ^ (m32 & 3));
      aoff[i][ks] = (wm * 64 + i * 32 + m32) * 64 + slot * 16;
      boff[i][ks] = (wn * 64 + i * 32 + m32) * 64 + slot * 16;
    }

  i32x16 acc[2][2];
#pragma unroll
  for (int i = 0; i < 2; ++i)
#pragma unroll
    for (int j = 0; j < 2; ++j)
#pragma unroll
      for (int r = 0; r < 16; ++r) acc[i][j][r] = 0;

  for (int kt = 0; kt < K_DIM / 64; ++kt) {
    __syncthreads();
    const int ke = kt * 64;
    __builtin_amdgcn_global_load_lds((GV*)(gA0 + ke), (LV*)lA0, 16, 0, 0);
    __builtin_amdgcn_global_load_lds((GV*)(gA1 + ke), (LV*)lA1, 16, 0, 0);
    __builtin_amdgcn_global_load_lds((GV*)(gB0 + ke), (LV*)lB0, 16, 0, 0);
    __builtin_amdgcn_global_load_lds((GV*)(gB1 + ke), (LV*)lB1, 16, 0, 0);
    __syncthreads();

    i32x4 af[2][2], bfr[2][2];
#pragma unroll
    for (int i = 0; i < 2; ++i)
#pragma unroll
      for (int ks = 0; ks < 2; ++ks) {
        af[i][ks] = *(const i32x4*)&As[aoff[i][ks]];
        bfr[i][ks] = *(const i32x4*)&Bs[boff[i][ks]];
      }

#pragma unroll
    for (int ks = 0; ks < 2; ++ks)
#pragma unroll
      for (int i = 0; i < 2; ++i)
#pragma unroll
        for (int j = 0; j < 2; ++j)
          acc[i][j] = __builtin_amdgcn_mfma_i32_32x32x32_i8(af[i][ks], bfr[j][ks],
                                                            acc[i][j], 0, 0, 0);
  }

  // ---- epilogue: C/D layout col=lane&31, row=(r&3)+8*(r>>2)+4*(lane>>5)
  float swv[2], bv[2];
#pragma unroll
  for (int j = 0; j < 2; ++j) {
    const int colg = bn * 128 + wn * 64 + j * 32 + m32;
    swv[j] = sw[colg];
    bv[j] = bias[colg];
  }

#pragma unroll
  for (int i = 0; i < 2; ++i) {
    const int rbase = bm * 128 + wm * 64 + i * 32 + 4 * half;
    float sxv[16];
#pragma unroll
    for (int r = 0; r < 16; ++r) sxv[r] = sx[rbase + (r & 3) + 8 * (r >> 2)];
#pragma unroll
    for (int j = 0; j < 2; ++j) {
      const int colg = bn * 128 + wn * 64 + j * 32 + m32;
#pragma unroll
      for (int r = 0; r < 16; ++r) {
        const int rowg = rbase + (r & 3) + 8 * (r >> 2);
        C[(size_t)rowg * N_DIM + colg] = (float)acc[i][j][r] * (sxv[r] * swv[j]) + bv[j];
      }
    }
  }
}

// ---------------------------------------------------------------------------
extern "C" void kernel_launch(void* const* d_in, const int* in_sizes, int n_in,
                              void* d_out, int out_size, void* d_ws, size_t ws_size,
                              hipStream_t stream) {
  const float* x = (const float*)d_in[0];     // (2,2048,4096) fp32
  const float* w = (const float*)d_in[1];     // (4096,4096) fp32 (pre-quantized)
  const float* bias = (const float*)d_in[2];  // (4096,) fp32

  char* xq = (char*)d_ws;                                   // 16 MB i8
  char* wq = xq + (size_t)M_DIM * K_DIM;                    // 16 MB i8
  float* sx = (float*)(wq + (size_t)N_DIM * K_DIM);         // 16 KB
  float* sw = sx + M_DIM;                                   // 16 KB
  float* out = (float*)d_out;

  prequant_kernel<<<2048, 256, 0, stream>>>(x, w, xq, wq, sx, sw);

  dim3 grid(N_DIM / 128, M_DIM / 128);
  gemm_i8<<<grid, 256, 0, stream>>>(xq, wq, sx, sw, bias, out);
}

// Round 4
// 247.709 us; speedup vs baseline: 1.4281x; 1.0958x over previous
//
#include <hip/hip_runtime.h>
#include <hip/hip_bf16.h>

#define M_DIM 4096
#define N_DIM 4096
#define K_DIM 4096

typedef __attribute__((ext_vector_type(4))) int i32x4;
typedef __attribute__((ext_vector_type(16))) int i32x16;

typedef __attribute__((address_space(1))) const void GV;
typedef __attribute__((address_space(3))) void LV;

// ---------------------------------------------------------------------------
// Fused pre-kernel.
//  blocks [0,1024):    hadamard (FWHT over 64 groups) + per-token absmax
//                      int8 quant; writes xq (i8) + sx (f32/token).
//  blocks [1024,2048): weight int8 recovery: per-row scale = absmax/127
//                      (exact inverse of setup-time per-channel QDQ);
//                      writes wq (i8) + sw (f32/row).
// ---------------------------------------------------------------------------
__global__ __launch_bounds__(256) void prequant_kernel(const float* __restrict__ x,
                                                       const float* __restrict__ w,
                                                       char* __restrict__ xq,
                                                       char* __restrict__ wq,
                                                       float* __restrict__ sx,
                                                       float* __restrict__ sw) {
  const int wave = threadIdx.x >> 6;
  const int lane = threadIdx.x & 63;

  if (blockIdx.x >= 1024) {
    // ---- weight row: recover integer codes exactly
    const int row = (blockIdx.x - 1024) * 4 + wave;
    const float* wp = w + (size_t)row * 4096;
    float4 v[16];
#pragma unroll
    for (int c = 0; c < 16; ++c) v[c] = *(const float4*)(wp + c * 256 + lane * 4);
    float amax = 0.f;
#pragma unroll
    for (int c = 0; c < 16; ++c)
      amax = fmaxf(amax, fmaxf(fmaxf(fabsf(v[c].x), fabsf(v[c].y)),
                               fmaxf(fabsf(v[c].z), fabsf(v[c].w))));
#pragma unroll
    for (int off = 32; off >= 1; off >>= 1) amax = fmaxf(amax, __shfl_xor(amax, off, 64));
    amax = fmaxf(amax, 1e-30f);
    const float inv = 127.0f / amax;  // w = iw*s with amax = 127*s  ->  w*inv = iw
    char* op = wq + (size_t)row * 4096;
#pragma unroll
    for (int c = 0; c < 16; ++c) {
      char4 o;
      o.x = (char)rintf(v[c].x * inv);
      o.y = (char)rintf(v[c].y * inv);
      o.z = (char)rintf(v[c].z * inv);
      o.w = (char)rintf(v[c].w * inv);
      *(char4*)(op + c * 256 + lane * 4) = o;
    }
    if (lane == 0) sw[row] = amax * (1.0f / 127.0f);
    return;
  }

  // ---- hadamard + per-token int8 quant
  const int tok = blockIdx.x * 4 + wave;
  const int gs = lane >> 4;  // quarter of g-space
  const int q = lane & 15;   // d-quad: d = q*4..q*4+3
  const float* xp = x + (size_t)tok * 4096;

  float4 v[16];  // lane holds g = gl*4+gs, gl=0..15, float4 over d
#pragma unroll
  for (int gl = 0; gl < 16; ++gl)
    v[gl] = *(const float4*)(xp + (gl * 4 + gs) * 64 + q * 4);

  // in-lane FWHT stages (g-bits 4,8,16,32 <=> gl-bits 1,2,4,8)
#pragma unroll
  for (int s = 1; s < 16; s <<= 1) {
#pragma unroll
    for (int i = 0; i < 16; ++i) {
      if ((i & s) == 0) {
        float4 a = v[i], b = v[i | s];
        v[i].x = a.x + b.x; v[i].y = a.y + b.y; v[i].z = a.z + b.z; v[i].w = a.w + b.w;
        v[i | s].x = a.x - b.x; v[i | s].y = a.y - b.y;
        v[i | s].z = a.z - b.z; v[i | s].w = a.w - b.w;
      }
    }
  }
  // cross-lane stages: g-bit 1 <=> lane^16, g-bit 2 <=> lane^32
#pragma unroll
  for (int st = 0; st < 2; ++st) {
    const int L = 16 << st;
    const bool hi = (lane & L) != 0;
#pragma unroll
    for (int i = 0; i < 16; ++i) {
      float4 t;
      t.x = __shfl_xor(v[i].x, L, 64);
      t.y = __shfl_xor(v[i].y, L, 64);
      t.z = __shfl_xor(v[i].z, L, 64);
      t.w = __shfl_xor(v[i].w, L, 64);
      if (hi) {
        v[i].x = t.x - v[i].x; v[i].y = t.y - v[i].y;
        v[i].z = t.z - v[i].z; v[i].w = t.w - v[i].w;
      } else {
        v[i].x += t.x; v[i].y += t.y; v[i].z += t.z; v[i].w += t.w;
      }
    }
  }

  float amax = 0.f;
#pragma unroll
  for (int i = 0; i < 16; ++i) {
    v[i].x *= 0.125f; v[i].y *= 0.125f; v[i].z *= 0.125f; v[i].w *= 0.125f;  // 1/sqrt(64)
    amax = fmaxf(amax, fmaxf(fmaxf(fabsf(v[i].x), fabsf(v[i].y)),
                             fmaxf(fabsf(v[i].z), fabsf(v[i].w))));
  }
#pragma unroll
  for (int off = 32; off >= 1; off >>= 1) amax = fmaxf(amax, __shfl_xor(amax, off, 64));

  const float s = fmaxf(amax * (1.0f / 127.0f), 1e-5f);  // reference clip
  const float inv = 1.0f / s;

  char* op = xq + (size_t)tok * 4096;
#pragma unroll
  for (int gl = 0; gl < 16; ++gl) {
    char4 o;
    o.x = (char)rintf(v[gl].x * inv);
    o.y = (char)rintf(v[gl].y * inv);
    o.z = (char)rintf(v[gl].z * inv);
    o.w = (char)rintf(v[gl].w * inv);
    *(char4*)(op + (gl * 4 + gs) * 64 + q * 4) = o;
  }
  if (lane == 0) sx[tok] = s;
}

// ---------------------------------------------------------------------------
// Exact int8 GEMM: C[m][n] = sx[m]*sw[n] * (sum_k ix[m][k]*iw[n][k]) + bias[n]
// 128x128 tile, BK=128 (i8, 32KB LDS total), 4 waves 2x2, each wave 2x2 of
// mfma_i32_32x32x32_i8, 4 K-chunks per LDS tile -> 32 K-iters, 64 barriers
// (vs 128 at BK=64). XOR-8 swizzle: 16B segment `seg` of row r lives in slot
// seg^(r&7) -> every 8-row group of a ds_read_b128 covers all 32 banks.
// Staging keeps global_load_lds's contiguous dest (tid*16 + c*4KB) by
// permuting the GLOBAL segment each thread fetches (same 1KB wave span).
// __launch_bounds__(256,3): pin 3 waves/SIMD (<=170 regs) so the bigger
// loop body can't drop occupancy to 2 (m132's failure mode).
// ---------------------------------------------------------------------------
__global__ __launch_bounds__(256, 3) void gemm_i8(const char* __restrict__ A,
                                                  const char* __restrict__ B,
                                                  const float* __restrict__ sx,
                                                  const float* __restrict__ sw,
                                                  const float* __restrict__ bias,
                                                  float* __restrict__ C) {
  __shared__ char As[128 * 128];
  __shared__ char Bs[128 * 128];

  const int tid = threadIdx.x;
  const int lane = tid & 63;
  const int wave = tid >> 6;
  const int bm = blockIdx.y, bn = blockIdx.x;
  const int wm = wave >> 1, wn = wave & 1;

  // ---- staging: thread tid stages 4x16B per matrix; chunk c -> LDS offset
  //      c*4096 + tid*16  == row (c*32 + tid>>3), slot tid&7.
  //      fetch global seg = (tid&7) ^ ((tid>>3)&7)   [row&7 == (tid>>3)&7]
  const int trow = tid >> 3;                       // 0..31
  const int tseg = (tid & 7) ^ (trow & 7);
  const char* gA = A + (size_t)(bm * 128 + trow) * K_DIM + tseg * 16;
  const char* gB = B + (size_t)(bn * 128 + trow) * K_DIM + tseg * 16;
  char* lA = &As[tid * 16];
  char* lB = &Bs[tid * 16];

  // ---- fragment addressing: row = w?*64 + i*32 + m32 (byte stride 128);
  //      logical seg = kc*2 + half, slot = seg ^ (row&7) = seg ^ (m32&7)
  const int m32 = lane & 31;
  const int half = lane >> 5;
  const int aBase = (wm * 64 + m32) * 128;
  const int bBase = (wn * 64 + m32) * 128;
  int sl[4];
#pragma unroll
  for (int kc = 0; kc < 4; ++kc) sl[kc] = ((kc * 2 + half) ^ (m32 & 7)) * 16;

  i32x16 acc[2][2];
#pragma unroll
  for (int i = 0; i < 2; ++i)
#pragma unroll
    for (int j = 0; j < 2; ++j)
#pragma unroll
      for (int r = 0; r < 16; ++r) acc[i][j][r] = 0;

  for (int kt = 0; kt < K_DIM / 128; ++kt) {
    __syncthreads();
    const size_t ke = (size_t)kt * 128;
#pragma unroll
    for (int c = 0; c < 4; ++c) {
      __builtin_amdgcn_global_load_lds((GV*)(gA + ke + (size_t)c * 32 * K_DIM),
                                       (LV*)(lA + c * 4096), 16, 0, 0);
      __builtin_amdgcn_global_load_lds((GV*)(gB + ke + (size_t)c * 32 * K_DIM),
                                       (LV*)(lB + c * 4096), 16, 0, 0);
    }
    __syncthreads();

#pragma unroll
    for (int kc = 0; kc < 4; ++kc) {
      i32x4 a0 = *(const i32x4*)&As[aBase + sl[kc]];
      i32x4 a1 = *(const i32x4*)&As[aBase + 4096 + sl[kc]];
      i32x4 b0 = *(const i32x4*)&Bs[bBase + sl[kc]];
      i32x4 b1 = *(const i32x4*)&Bs[bBase + 4096 + sl[kc]];
      acc[0][0] = __builtin_amdgcn_mfma_i32_32x32x32_i8(a0, b0, acc[0][0], 0, 0, 0);
      acc[0][1] = __builtin_amdgcn_mfma_i32_32x32x32_i8(a0, b1, acc[0][1], 0, 0, 0);
      acc[1][0] = __builtin_amdgcn_mfma_i32_32x32x32_i8(a1, b0, acc[1][0], 0, 0, 0);
      acc[1][1] = __builtin_amdgcn_mfma_i32_32x32x32_i8(a1, b1, acc[1][1], 0, 0, 0);
    }
  }

  // ---- epilogue: C/D layout col=lane&31, row=(r&3)+8*(r>>2)+4*(lane>>5)
  float swv[2], bv[2];
#pragma unroll
  for (int j = 0; j < 2; ++j) {
    const int colg = bn * 128 + wn * 64 + j * 32 + m32;
    swv[j] = sw[colg];
    bv[j] = bias[colg];
  }

#pragma unroll
  for (int i = 0; i < 2; ++i) {
    const int rbase = bm * 128 + wm * 64 + i * 32 + 4 * half;
    float sxv[16];
#pragma unroll
    for (int r = 0; r < 16; ++r) sxv[r] = sx[rbase + (r & 3) + 8 * (r >> 2)];
#pragma unroll
    for (int j = 0; j < 2; ++j) {
      const int colg = bn * 128 + wn * 64 + j * 32 + m32;
#pragma unroll
      for (int r = 0; r < 16; ++r) {
        const int rowg = rbase + (r & 3) + 8 * (r >> 2);
        C[(size_t)rowg * N_DIM + colg] = (float)acc[i][j][r] * (sxv[r] * swv[j]) + bv[j];
      }
    }
  }
}

// ---------------------------------------------------------------------------
extern "C" void kernel_launch(void* const* d_in, const int* in_sizes, int n_in,
                              void* d_out, int out_size, void* d_ws, size_t ws_size,
                              hipStream_t stream) {
  const float* x = (const float*)d_in[0];     // (2,2048,4096) fp32
  const float* w = (const float*)d_in[1];     // (4096,4096) fp32 (pre-quantized)
  const float* bias = (const float*)d_in[2];  // (4096,) fp32

  char* xq = (char*)d_ws;                                   // 16 MB i8
  char* wq = xq + (size_t)M_DIM * K_DIM;                    // 16 MB i8
  float* sx = (float*)(wq + (size_t)N_DIM * K_DIM);         // 16 KB
  float* sw = sx + M_DIM;                                   // 16 KB
  float* out = (float*)d_out;

  prequant_kernel<<<2048, 256, 0, stream>>>(x, w, xq, wq, sx, sw);

  dim3 grid(N_DIM / 128, M_DIM / 128);
  gemm_i8<<<grid, 256, 0, stream>>>(xq, wq, sx, sw, bias, out);
}